// Round 12
// baseline (261.280 us; speedup 1.0000x reference)
//
#include <hip/hip_runtime.h>

// Dense dilated KNN graph. B=2, C=64, N=8192, k_total=18, keep ::2 -> 9.
// r12: prep pre-splits bf16 hi/lo (pre-swizzled) -> knn_part staging is a pure
// identity copy (no split VALU); A-frags from global + sign-flip (A=-Q).
// prep2 overwrites hi/lo region with f32 pts after knn_part (ws 6.88MB, proven
// envelope). Finalize: 8 thr/row, padded LDS, 2-stage merge.

#define NPTS  8192
#define CHN   64
#define NB    2
#define KF    18
#define KC    8
#define KM    20
#define KOUT  9
#define NPART 4
#define TPB   32

typedef unsigned u32;
typedef unsigned short u16;
typedef unsigned long long u64;
typedef __attribute__((ext_vector_type(4))) unsigned u32x4;
typedef __attribute__((ext_vector_type(8))) short bf16x8;
typedef __attribute__((ext_vector_type(4))) float f32x4;

__device__ __forceinline__ u32 umin32(u32 a, u32 b) { return a < b ? a : b; }
__device__ __forceinline__ u32 umax32(u32 a, u32 b) { return a > b ? a : b; }

__device__ __forceinline__ u32 mono32(float f) {
  const u32 u = __float_as_uint(f);
  const u32 s = (u32)((int)u >> 31);
  return u ^ (s | 0x80000000u);
}

template <int KK>
__device__ __forceinline__ void insmm(u32 key, u32 (&d)[KK]) {
#pragma unroll
  for (int k = KK - 1; k >= 1; --k) d[k] = umax32(d[k - 1], umin32(d[k], key));
  d[0] = umin32(d[0], key);
}

template <int KK>
__device__ __forceinline__ void ins64(u64 key, u64 (&d)[KK]) {
  if (key < d[KK - 1]) {
#pragma unroll
    for (int k = KK - 1; k >= 1; --k) {
      const bool up = d[k - 1] > key;
      const bool here = (!up) && (d[k] > key);
      d[k] = up ? d[k - 1] : (here ? key : d[k]);
    }
    if (d[0] > key) d[0] = key;
  }
}

__device__ __forceinline__ void np_normalize(const float* __restrict__ xb,
                                             float (&v)[CHN]) {
  float ss = 0.f;
#pragma unroll
  for (int c = 0; c < CHN; ++c) {
    v[c] = xb[(size_t)c * NPTS];
    ss = __fadd_rn(ss, __fmul_rn(v[c], v[c]));
  }
  const float den = fmaxf(__fsqrt_rn(ss), 1e-12f);
#pragma unroll
  for (int c = 0; c < CHN; ++c) v[c] = __fdiv_rn(v[c], den);
}

// ---------------- kernel 1: normalize + sq + PRE-SPLIT hi/lo ----------------
__global__ __launch_bounds__(128) void prep_kernel(
    const float* __restrict__ x, u32* __restrict__ hib, u32* __restrict__ lob,
    float* __restrict__ sq) {
  const int b = blockIdx.x >> 6;
  const int n = ((blockIdx.x & 63) << 7) + threadIdx.x;
  float v[CHN];
  np_normalize(x + (size_t)b * CHN * NPTS + n, v);
  float r[8];
#pragma unroll
  for (int j = 0; j < 8; ++j) r[j] = __fmul_rn(v[j], v[j]);
#pragma unroll
  for (int blk = 1; blk < 8; ++blk)
#pragma unroll
    for (int j = 0; j < 8; ++j)
      r[j] = __fadd_rn(r[j], __fmul_rn(v[8 * blk + j], v[8 * blk + j]));
  const float t0 = __fadd_rn(r[0], r[1]);
  const float t1 = __fadd_rn(r[2], r[3]);
  const float t2 = __fadd_rn(r[4], r[5]);
  const float t3 = __fadd_rn(r[6], r[7]);
  sq[(b << 13) + n] = __fadd_rn(__fadd_rn(t0, t1), __fadd_rn(t2, t3));
  u32* hd = hib + (size_t)((b << 13) + n) * 32;
  u32* ld = lob + (size_t)((b << 13) + n) * 32;
  const int key = n & 7;
#pragma unroll
  for (int q = 0; q < 8; ++q) {
    u32 h[4], l[4];
#pragma unroll
    for (int p2 = 0; p2 < 4; ++p2) {
      const float a = v[8 * q + 2 * p2];
      const float c = v[8 * q + 2 * p2 + 1];
      const u32 ba = __float_as_uint(a), bc = __float_as_uint(c);
      const float la = a - __uint_as_float(ba & 0xffff0000u);
      const float lc = c - __uint_as_float(bc & 0xffff0000u);
      h[p2] = __builtin_amdgcn_perm(bc, ba, 0x07060302u);
      l[p2] = __builtin_amdgcn_perm(__float_as_uint(lc), __float_as_uint(la),
                                    0x07060302u);
    }
    const int pq = (q ^ key) << 2;
    *(u32x4*)(hd + pq) = (u32x4){h[0], h[1], h[2], h[3]};
    *(u32x4*)(ld + pq) = (u32x4){l[0], l[1], l[2], l[3]};
  }
}

// ---------------- kernel 1b: write f32 pts (over hi/lo region) ----------------
__global__ __launch_bounds__(128) void prep2_kernel(
    const float* __restrict__ x, float* __restrict__ pts) {
  const int b = blockIdx.x >> 6;
  const int n = ((blockIdx.x & 63) << 7) + threadIdx.x;
  float v[CHN];
  np_normalize(x + (size_t)b * CHN * NPTS + n, v);
  float4* dst = (float4*)(pts + (size_t)(b * NPTS + n) * CHN);
#pragma unroll
  for (int u = 0; u < 16; ++u)
    dst[u] = make_float4(v[4 * u], v[4 * u + 1], v[4 * u + 2], v[4 * u + 3]);
}

// ---------------- kernel 2: MFMA GEMM + reg-select + in-place merge ----------------
__global__ __launch_bounds__(256, 3) void knn_part_kernel(
    const u32* __restrict__ hib, const u32* __restrict__ lob,
    const float* __restrict__ sq, u16* __restrict__ cand) {
  __shared__ __align__(16) u32 pp[2][4096];
  __shared__ float sqp[2][64];

  const int tid = threadIdx.x;
  const int vb = ((blockIdx.x & 7) << 7) + (blockIdx.x >> 3);
  const int part = vb >> 8;
  const int w = vb & 255;
  const int b = w >> 7;
  const int qbase = (w & 127) << 6;
  const int t_lo = part << 5;
  const u32* __restrict__ hb_ = hib + ((size_t)b << 18);
  const u32* __restrict__ lb_ = lob + ((size_t)b << 18);
  const float* __restrict__ sqb = sq + (b << 13);

  const int lane = tid & 63, wid = tid >> 6;
  const int qoff = (wid & 1) << 5;
  const int moff = (wid >> 1) << 5;
  const int l15 = lane & 15;
  const int h4 = lane >> 4;
  const int sw = l15 & 7;

  {
    const u32* sH = hb_ + ((size_t)t_lo << 11);
    const u32* sL = lb_ + ((size_t)t_lo << 11);
    *(u32x4*)(pp[0] + (tid << 2)) = *(const u32x4*)(sH + (tid << 2));
    *(u32x4*)(pp[0] + 1024 + (tid << 2)) = *(const u32x4*)(sH + 1024 + (tid << 2));
    *(u32x4*)(pp[0] + 2048 + (tid << 2)) = *(const u32x4*)(sL + (tid << 2));
    *(u32x4*)(pp[0] + 3072 + (tid << 2)) = *(const u32x4*)(sL + 1024 + (tid << 2));
    if (tid < 64) sqp[0][tid] = (sqb[(t_lo << 6) + tid] + 2.f) * 0.5f;
  }

  bf16x8 ah[2][2], al[2][2];
#pragma unroll
  for (int g = 0; g < 2; ++g)
#pragma unroll
    for (int s = 0; s < 2; ++s) {
      const int row = qbase + qoff + (g << 4) + l15;
      const int off = row * 32 + ((((s << 2) + h4) ^ sw) << 2);
      u32x4 hv = *(const u32x4*)(hb_ + off);
      u32x4 lv = *(const u32x4*)(lb_ + off);
      hv.x ^= 0x80008000u; hv.y ^= 0x80008000u;
      hv.z ^= 0x80008000u; hv.w ^= 0x80008000u;
      lv.x ^= 0x80008000u; lv.y ^= 0x80008000u;
      lv.z ^= 0x80008000u; lv.w ^= 0x80008000u;
      ah[g][s] = __builtin_bit_cast(bf16x8, hv);
      al[g][s] = __builtin_bit_cast(bf16x8, lv);
    }
  __syncthreads();

  u32 d[2][4][KC];
#pragma unroll
  for (int g = 0; g < 2; ++g)
#pragma unroll
    for (int i = 0; i < 4; ++i)
#pragma unroll
      for (int k = 0; k < KC; ++k) d[g][i][k] = 0xffffffffu;

  for (int tau = 0; tau < TPB; ++tau) {
    const int cur = tau & 1;
    u32x4 st[4];
    float sqv = 0.f;
    const bool more = (tau + 1) < TPB;
    if (more) {
      const u32* sH = hb_ + ((size_t)(t_lo + tau + 1) << 11);
      const u32* sL = lb_ + ((size_t)(t_lo + tau + 1) << 11);
      st[0] = *(const u32x4*)(sH + (tid << 2));
      st[1] = *(const u32x4*)(sH + 1024 + (tid << 2));
      st[2] = *(const u32x4*)(sL + (tid << 2));
      st[3] = *(const u32x4*)(sL + 1024 + (tid << 2));
      if (tid < 64) sqv = sqb[((t_lo + tau + 1) << 6) + tid];
    }
    const u32* ppc = pp[cur];
#pragma unroll
    for (int f = 0; f < 2; ++f) {
      const int m_l = moff + (f << 4) + l15;
      const float sqm = sqp[cur][m_l];
      f32x4 acc[2];
      acc[0] = (f32x4){sqm, sqm, sqm, sqm};
      acc[1] = acc[0];
#pragma unroll
      for (int s = 0; s < 2; ++s) {
        const u32* hp = ppc + m_l * 32 + ((((s << 2) + h4) ^ sw) << 2);
        const bf16x8 bh = __builtin_bit_cast(bf16x8, *(const u32x4*)hp);
        const bf16x8 bl = __builtin_bit_cast(bf16x8, *(const u32x4*)(hp + 2048));
        acc[0] = __builtin_amdgcn_mfma_f32_16x16x32_bf16(ah[0][s], bh, acc[0], 0, 0, 0);
        acc[1] = __builtin_amdgcn_mfma_f32_16x16x32_bf16(ah[1][s], bh, acc[1], 0, 0, 0);
        acc[0] = __builtin_amdgcn_mfma_f32_16x16x32_bf16(al[0][s], bh, acc[0], 0, 0, 0);
        acc[1] = __builtin_amdgcn_mfma_f32_16x16x32_bf16(al[1][s], bh, acc[1], 0, 0, 0);
        acc[0] = __builtin_amdgcn_mfma_f32_16x16x32_bf16(ah[0][s], bl, acc[0], 0, 0, 0);
        acc[1] = __builtin_amdgcn_mfma_f32_16x16x32_bf16(ah[1][s], bl, acc[1], 0, 0, 0);
      }
      const u32 lidx = (u32)((tau << 6) + m_l);
#pragma unroll
      for (int g = 0; g < 2; ++g)
#pragma unroll
        for (int i = 0; i < 4; ++i) {
          const u32 keyv = (__float_as_uint(acc[g][i]) & 0xfffff000u) | lidx;
          insmm<KC>(keyv, d[g][i]);
        }
    }
    if (more) {
      u32* wp = pp[cur ^ 1];
      *(u32x4*)(wp + (tid << 2)) = st[0];
      *(u32x4*)(wp + 1024 + (tid << 2)) = st[1];
      *(u32x4*)(wp + 2048 + (tid << 2)) = st[2];
      *(u32x4*)(wp + 3072 + (tid << 2)) = st[3];
      if (tid < 64) sqp[cur ^ 1][tid] = (sqv + 2.f) * 0.5f;
    }
    __syncthreads();
  }

  u32* mg = &pp[0][0];
  const int stream = ((wid >> 1) << 4) + l15;
  const int rcb = ((wid & 1) << 4) + (h4 << 2);
#pragma unroll
  for (int chunk = 0; chunk < 2; ++chunk) {
#pragma unroll
    for (int i = 0; i < 4; ++i) {
      u32* wr = mg + ((rcb + i) * 32 + stream) * 8;
      u32x4 a, c;
      a.x = d[chunk][i][0]; a.y = d[chunk][i][1];
      a.z = d[chunk][i][2]; a.w = d[chunk][i][3];
      c.x = d[chunk][i][4]; c.y = d[chunk][i][5];
      c.z = d[chunk][i][6]; c.w = d[chunk][i][7];
      *(u32x4*)wr = a;
      *(u32x4*)(wr + 4) = c;
    }
    __syncthreads();
    {
      const int rowc = tid >> 3, oct = tid & 7;
      u32* base = mg + rowc * 256 + oct * 32;
      u32 m1[14];
#pragma unroll
      for (int k = 0; k < 14; ++k) m1[k] = 0xffffffffu;
#pragma unroll
      for (int j = 0; j < 8; ++j) {
        const u32x4 k4 = *(const u32x4*)(base + (j << 2));
        insmm<14>(k4.x, m1);
        insmm<14>(k4.y, m1);
        insmm<14>(k4.z, m1);
        insmm<14>(k4.w, m1);
      }
#pragma unroll
      for (int k = 0; k < 14; ++k) base[k] = m1[k];
    }
    __syncthreads();
    if (tid < 64) {
      const int rowc = tid >> 1, half = tid & 1;
      u32* rb = mg + rowc * 256 + half * 128;
      u32 m2[KM];
#pragma unroll
      for (int k = 0; k < KM; ++k) m2[k] = 0xffffffffu;
#pragma unroll
      for (int o = 0; o < 4; ++o) {
        const u32* p = rb + o * 32;
        for (int j = 0; j < 14; ++j) insmm<KM>(p[j], m2);
      }
#pragma unroll
      for (int k = 0; k < KM; ++k) rb[k] = m2[k];
    }
    __syncthreads();
    if (tid < 32) {
      u32 m3[KM];
#pragma unroll
      for (int k = 0; k < KM; ++k) m3[k] = 0xffffffffu;
      const u32* p0 = mg + tid * 256;
      for (int j = 0; j < KM; ++j) insmm<KM>(p0[j], m3);
      const u32* p1 = mg + tid * 256 + 128;
      for (int j = 0; j < KM; ++j) insmm<KM>(p1[j], m3);
      const int row = ((tid >> 4) << 5) + (chunk << 4) + (tid & 15);
      const int rg = (b << 13) + qbase + row;
      u16* cw = cand + (size_t)rg * (NPART * KM) + part * KM;
#pragma unroll
      for (int k = 0; k < KM; ++k)
        cw[k] = (u16)((part << 11) + (m3[k] & 0xfffu));
    }
    __syncthreads();
  }
}

// ---------------- kernel 3: bit-exact np-fp32 rescore + output ----------------
__global__ __launch_bounds__(512) void finalize_kernel(
    const float* __restrict__ pts, const float* __restrict__ sq,
    const u16* __restrict__ cand, int* __restrict__ out) {
  __shared__ u64 ex[64 * 81];
  __shared__ u64 hf[128 * 19];
  const int tid = threadIdx.x;
  const int rl = tid >> 3, sub = tid & 7;
  const int row = (blockIdx.x << 6) + rl;
  const int b = row >> 13;
  const float sqn = sq[row];
  const float* __restrict__ qrow = pts + ((size_t)row << 6);
  const float* __restrict__ sqb = sq + (b << 13);
  const u16* __restrict__ cr = cand + (size_t)row * 80 + sub * 10;
  u64* exw = ex + rl * 81 + sub * 10;
#pragma unroll 2
  for (int j = 0; j < 10; ++j) {
    const int ix = cr[j];
    const float* __restrict__ pv = pts + ((size_t)((b << 13) + ix) << 6);
    float dot = 0.f;
#pragma unroll
    for (int c = 0; c < CHN; ++c)
      dot = __fadd_rn(dot, __fmul_rn(qrow[c], pv[c]));
    const float dist =
        __fadd_rn(__fsub_rn(sqn, __fmul_rn(2.0f, dot)), sqb[ix]);
    exw[j] = ((u64)mono32(dist) << 32) | (u32)ix;
  }
  __syncthreads();
  if (tid < 128) {
    const int r2 = tid >> 1, hv = tid & 1;
    u64 m18[KF];
#pragma unroll
    for (int k = 0; k < KF; ++k) m18[k] = ~0ull;
    const u64* p = ex + r2 * 81 + hv * 40;
    for (int j = 0; j < 40; ++j) ins64<KF>(p[j], m18);
    u64* wr = hf + tid * 19;
#pragma unroll
    for (int k = 0; k < KF; ++k) wr[k] = m18[k];
  }
  __syncthreads();
  if (tid < 64) {
    u64 m18[KF];
#pragma unroll
    for (int k = 0; k < KF; ++k) m18[k] = ~0ull;
    const u64* p0 = hf + (tid << 1) * 19;
    const u64* p1 = hf + ((tid << 1) + 1) * 19;
    for (int j = 0; j < KF; ++j) ins64<KF>(p0[j], m18);
    for (int j = 0; j < KF; ++j) ins64<KF>(p1[j], m18);
    const int row2 = (blockIdx.x << 6) + tid;
    int* o0 = out + (size_t)row2 * KOUT;
    int* o1 = o0 + NB * NPTS * KOUT;
#pragma unroll
    for (int k = 0; k < KOUT; ++k) {
      o0[k] = (int)(m18[2 * k] & 0xffffffffu);
      o1[k] = row2 & 8191;
    }
  }
}

// ---------------- launcher ----------------
extern "C" void kernel_launch(void* const* d_in, const int* in_sizes, int n_in,
                              void* d_out, int out_size, void* d_ws, size_t ws_size,
                              hipStream_t stream) {
  const float* x = (const float*)d_in[0];
  u32* hib = (u32*)d_ws;                                // 2MB
  u32* lob = hib + (size_t)NB * NPTS * 32;              // 2MB
  float* pts = (float*)d_ws;                            // overlays hi/lo (4MB)
  float* sqg = (float*)(hib + (size_t)NB * NPTS * 64);  // @4MB, 64KB
  u16* cand = (u16*)(sqg + NB * NPTS);                  // 2.62MB
  int* out = (int*)d_out;
  prep_kernel<<<dim3(128), dim3(128), 0, stream>>>(x, hib, lob, sqg);
  knn_part_kernel<<<dim3(1024), dim3(256), 0, stream>>>(hib, lob, sqg, cand);
  prep2_kernel<<<dim3(128), dim3(128), 0, stream>>>(x, pts);
  finalize_kernel<<<dim3(256), dim3(512), 0, stream>>>(pts, sqg, cand, out);
}

// Round 13
// 228.303 us; speedup vs baseline: 1.1444x; 1.1444x over previous
//
#include <hip/hip_runtime.h>

// Dense dilated KNN graph. B=2, C=64, N=8192, k_total=18, keep ::2 -> 9.
// r13 = r12 + (a) v_med3_u32 insert stages (max(a,min(b,k)) == med3(a,b,k)
// under sorted invariant; 15->8 VALU per insert), (b) global_load_lds width-16
// staging (identity copy, lane-linear dest -> HW direct-to-LDS; no ds_write,
// no st[] regs). Everything else identical to r12.

#define NPTS  8192
#define CHN   64
#define NB    2
#define KF    18
#define KC    8
#define KM    20
#define KOUT  9
#define NPART 4
#define TPB   32

typedef unsigned u32;
typedef unsigned short u16;
typedef unsigned long long u64;
typedef __attribute__((ext_vector_type(4))) unsigned u32x4;
typedef __attribute__((ext_vector_type(8))) short bf16x8;
typedef __attribute__((ext_vector_type(4))) float f32x4;

__device__ __forceinline__ u32 umin32(u32 a, u32 b) { return a < b ? a : b; }
__device__ __forceinline__ u32 umax32(u32 a, u32 b) { return a > b ? a : b; }

__device__ __forceinline__ u32 mono32(float f) {
  const u32 u = __float_as_uint(f);
  const u32 s = (u32)((int)u >> 31);
  return u ^ (s | 0x80000000u);
}

// one insert stage: d[k] = med3(d[k-1], d[k], key)  (requires d sorted asc)
__device__ __forceinline__ u32 med3u(u32 a, u32 b, u32 c) {
  u32 r;
  asm("v_med3_u32 %0, %1, %2, %3" : "=v"(r) : "v"(a), "v"(b), "v"(c));
  return r;
}

template <int KK>
__device__ __forceinline__ void insmm(u32 key, u32 (&d)[KK]) {
#pragma unroll
  for (int k = KK - 1; k >= 1; --k) d[k] = med3u(d[k - 1], d[k], key);
  d[0] = umin32(d[0], key);
}

template <int KK>
__device__ __forceinline__ void ins64(u64 key, u64 (&d)[KK]) {
  if (key < d[KK - 1]) {
#pragma unroll
    for (int k = KK - 1; k >= 1; --k) {
      const bool up = d[k - 1] > key;
      const bool here = (!up) && (d[k] > key);
      d[k] = up ? d[k - 1] : (here ? key : d[k]);
    }
    if (d[0] > key) d[0] = key;
  }
}

// direct global -> LDS, 16B per lane (dest must be lane-linear: base+lane*16)
__device__ __forceinline__ void gload_lds16(const u32* g, u32* l) {
  __builtin_amdgcn_global_load_lds(
      (const __attribute__((address_space(1))) u32*)g,
      (__attribute__((address_space(3))) u32*)l, 16, 0, 0);
}

__device__ __forceinline__ void np_normalize(const float* __restrict__ xb,
                                             float (&v)[CHN]) {
  float ss = 0.f;
#pragma unroll
  for (int c = 0; c < CHN; ++c) {
    v[c] = xb[(size_t)c * NPTS];
    ss = __fadd_rn(ss, __fmul_rn(v[c], v[c]));
  }
  const float den = fmaxf(__fsqrt_rn(ss), 1e-12f);
#pragma unroll
  for (int c = 0; c < CHN; ++c) v[c] = __fdiv_rn(v[c], den);
}

// ---------------- kernel 1: normalize + sq + PRE-SPLIT hi/lo ----------------
__global__ __launch_bounds__(128) void prep_kernel(
    const float* __restrict__ x, u32* __restrict__ hib, u32* __restrict__ lob,
    float* __restrict__ sq) {
  const int b = blockIdx.x >> 6;
  const int n = ((blockIdx.x & 63) << 7) + threadIdx.x;
  float v[CHN];
  np_normalize(x + (size_t)b * CHN * NPTS + n, v);
  float r[8];
#pragma unroll
  for (int j = 0; j < 8; ++j) r[j] = __fmul_rn(v[j], v[j]);
#pragma unroll
  for (int blk = 1; blk < 8; ++blk)
#pragma unroll
    for (int j = 0; j < 8; ++j)
      r[j] = __fadd_rn(r[j], __fmul_rn(v[8 * blk + j], v[8 * blk + j]));
  const float t0 = __fadd_rn(r[0], r[1]);
  const float t1 = __fadd_rn(r[2], r[3]);
  const float t2 = __fadd_rn(r[4], r[5]);
  const float t3 = __fadd_rn(r[6], r[7]);
  sq[(b << 13) + n] = __fadd_rn(__fadd_rn(t0, t1), __fadd_rn(t2, t3));
  u32* hd = hib + (size_t)((b << 13) + n) * 32;
  u32* ld = lob + (size_t)((b << 13) + n) * 32;
  const int key = n & 7;
#pragma unroll
  for (int q = 0; q < 8; ++q) {
    u32 h[4], l[4];
#pragma unroll
    for (int p2 = 0; p2 < 4; ++p2) {
      const float a = v[8 * q + 2 * p2];
      const float c = v[8 * q + 2 * p2 + 1];
      const u32 ba = __float_as_uint(a), bc = __float_as_uint(c);
      const float la = a - __uint_as_float(ba & 0xffff0000u);
      const float lc = c - __uint_as_float(bc & 0xffff0000u);
      h[p2] = __builtin_amdgcn_perm(bc, ba, 0x07060302u);
      l[p2] = __builtin_amdgcn_perm(__float_as_uint(lc), __float_as_uint(la),
                                    0x07060302u);
    }
    const int pq = (q ^ key) << 2;
    *(u32x4*)(hd + pq) = (u32x4){h[0], h[1], h[2], h[3]};
    *(u32x4*)(ld + pq) = (u32x4){l[0], l[1], l[2], l[3]};
  }
}

// ---------------- kernel 1b: write f32 pts (over hi/lo region) ----------------
__global__ __launch_bounds__(128) void prep2_kernel(
    const float* __restrict__ x, float* __restrict__ pts) {
  const int b = blockIdx.x >> 6;
  const int n = ((blockIdx.x & 63) << 7) + threadIdx.x;
  float v[CHN];
  np_normalize(x + (size_t)b * CHN * NPTS + n, v);
  float4* dst = (float4*)(pts + (size_t)(b * NPTS + n) * CHN);
#pragma unroll
  for (int u = 0; u < 16; ++u)
    dst[u] = make_float4(v[4 * u], v[4 * u + 1], v[4 * u + 2], v[4 * u + 3]);
}

// ---------------- kernel 2: MFMA GEMM + reg-select + in-place merge ----------------
__global__ __launch_bounds__(256, 3) void knn_part_kernel(
    const u32* __restrict__ hib, const u32* __restrict__ lob,
    const float* __restrict__ sq, u16* __restrict__ cand) {
  __shared__ __align__(16) u32 pp[2][4096];
  __shared__ float sqp[2][64];

  const int tid = threadIdx.x;
  const int vb = ((blockIdx.x & 7) << 7) + (blockIdx.x >> 3);
  const int part = vb >> 8;
  const int w = vb & 255;
  const int b = w >> 7;
  const int qbase = (w & 127) << 6;
  const int t_lo = part << 5;
  const u32* __restrict__ hb_ = hib + ((size_t)b << 18);
  const u32* __restrict__ lb_ = lob + ((size_t)b << 18);
  const float* __restrict__ sqb = sq + (b << 13);

  const int lane = tid & 63, wid = tid >> 6;
  const int qoff = (wid & 1) << 5;
  const int moff = (wid >> 1) << 5;
  const int l15 = lane & 15;
  const int h4 = lane >> 4;
  const int sw = l15 & 7;

  // ---- prologue: stage tile t_lo direct-to-LDS + sqp
  {
    const u32* sH = hb_ + ((size_t)t_lo << 11);
    const u32* sL = lb_ + ((size_t)t_lo << 11);
    gload_lds16(sH + (tid << 2), pp[0] + (tid << 2));
    gload_lds16(sH + 1024 + (tid << 2), pp[0] + 1024 + (tid << 2));
    gload_lds16(sL + (tid << 2), pp[0] + 2048 + (tid << 2));
    gload_lds16(sL + 1024 + (tid << 2), pp[0] + 3072 + (tid << 2));
    if (tid < 64) sqp[0][tid] = (sqb[(t_lo << 6) + tid] + 2.f) * 0.5f;
  }

  // ---- A fragments from GLOBAL presplit, negated (A = -Q)
  bf16x8 ah[2][2], al[2][2];
#pragma unroll
  for (int g = 0; g < 2; ++g)
#pragma unroll
    for (int s = 0; s < 2; ++s) {
      const int row = qbase + qoff + (g << 4) + l15;
      const int off = row * 32 + ((((s << 2) + h4) ^ sw) << 2);
      u32x4 hv = *(const u32x4*)(hb_ + off);
      u32x4 lv = *(const u32x4*)(lb_ + off);
      hv.x ^= 0x80008000u; hv.y ^= 0x80008000u;
      hv.z ^= 0x80008000u; hv.w ^= 0x80008000u;
      lv.x ^= 0x80008000u; lv.y ^= 0x80008000u;
      lv.z ^= 0x80008000u; lv.w ^= 0x80008000u;
      ah[g][s] = __builtin_bit_cast(bf16x8, hv);
      al[g][s] = __builtin_bit_cast(bf16x8, lv);
    }
  __syncthreads();   // drains prologue gload_lds (vmcnt) too

  u32 d[2][4][KC];
#pragma unroll
  for (int g = 0; g < 2; ++g)
#pragma unroll
    for (int i = 0; i < 4; ++i)
#pragma unroll
      for (int k = 0; k < KC; ++k) d[g][i][k] = 0xffffffffu;

  for (int tau = 0; tau < TPB; ++tau) {
    const int cur = tau & 1;
    float sqv = 0.f;
    const bool more = (tau + 1) < TPB;
    if (more) {   // issue next-tile direct-to-LDS loads (land in pp[cur^1])
      const u32* sH = hb_ + ((size_t)(t_lo + tau + 1) << 11);
      const u32* sL = lb_ + ((size_t)(t_lo + tau + 1) << 11);
      u32* wp = pp[cur ^ 1];
      gload_lds16(sH + (tid << 2), wp + (tid << 2));
      gload_lds16(sH + 1024 + (tid << 2), wp + 1024 + (tid << 2));
      gload_lds16(sL + (tid << 2), wp + 2048 + (tid << 2));
      gload_lds16(sL + 1024 + (tid << 2), wp + 3072 + (tid << 2));
      if (tid < 64) sqv = sqb[((t_lo + tau + 1) << 6) + tid];
    }
    // ---- MFMA: acc = (sq_m+2)/2 - q.p (positive -> raw-bit key) + select
    const u32* ppc = pp[cur];
#pragma unroll
    for (int f = 0; f < 2; ++f) {
      const int m_l = moff + (f << 4) + l15;
      const float sqm = sqp[cur][m_l];
      f32x4 acc[2];
      acc[0] = (f32x4){sqm, sqm, sqm, sqm};
      acc[1] = acc[0];
#pragma unroll
      for (int s = 0; s < 2; ++s) {
        const u32* hp = ppc + m_l * 32 + ((((s << 2) + h4) ^ sw) << 2);
        const bf16x8 bh = __builtin_bit_cast(bf16x8, *(const u32x4*)hp);
        const bf16x8 bl = __builtin_bit_cast(bf16x8, *(const u32x4*)(hp + 2048));
        acc[0] = __builtin_amdgcn_mfma_f32_16x16x32_bf16(ah[0][s], bh, acc[0], 0, 0, 0);
        acc[1] = __builtin_amdgcn_mfma_f32_16x16x32_bf16(ah[1][s], bh, acc[1], 0, 0, 0);
        acc[0] = __builtin_amdgcn_mfma_f32_16x16x32_bf16(al[0][s], bh, acc[0], 0, 0, 0);
        acc[1] = __builtin_amdgcn_mfma_f32_16x16x32_bf16(al[1][s], bh, acc[1], 0, 0, 0);
        acc[0] = __builtin_amdgcn_mfma_f32_16x16x32_bf16(ah[0][s], bl, acc[0], 0, 0, 0);
        acc[1] = __builtin_amdgcn_mfma_f32_16x16x32_bf16(ah[1][s], bl, acc[1], 0, 0, 0);
      }
      const u32 lidx = (u32)((tau << 6) + m_l);
#pragma unroll
      for (int g = 0; g < 2; ++g)
#pragma unroll
        for (int i = 0; i < 4; ++i) {
          const u32 keyv = (__float_as_uint(acc[g][i]) & 0xfffff000u) | lidx;
          insmm<KC>(keyv, d[g][i]);
        }
    }
    if (more && tid < 64) sqp[cur ^ 1][tid] = (sqv + 2.f) * 0.5f;
    __syncthreads();   // drains gload_lds; pp[cur^1] ready for next iter
  }

  // ---- in-place 3-level merge in pp (two 32-row chunks)
  u32* mg = &pp[0][0];
  const int stream = ((wid >> 1) << 4) + l15;
  const int rcb = ((wid & 1) << 4) + (h4 << 2);
#pragma unroll
  for (int chunk = 0; chunk < 2; ++chunk) {
#pragma unroll
    for (int i = 0; i < 4; ++i) {
      u32* wr = mg + ((rcb + i) * 32 + stream) * 8;
      u32x4 a, c;
      a.x = d[chunk][i][0]; a.y = d[chunk][i][1];
      a.z = d[chunk][i][2]; a.w = d[chunk][i][3];
      c.x = d[chunk][i][4]; c.y = d[chunk][i][5];
      c.z = d[chunk][i][6]; c.w = d[chunk][i][7];
      *(u32x4*)wr = a;
      *(u32x4*)(wr + 4) = c;
    }
    __syncthreads();
    {
      const int rowc = tid >> 3, oct = tid & 7;
      u32* base = mg + rowc * 256 + oct * 32;
      u32 m1[14];
#pragma unroll
      for (int k = 0; k < 14; ++k) m1[k] = 0xffffffffu;
#pragma unroll
      for (int j = 0; j < 8; ++j) {
        const u32x4 k4 = *(const u32x4*)(base + (j << 2));
        insmm<14>(k4.x, m1);
        insmm<14>(k4.y, m1);
        insmm<14>(k4.z, m1);
        insmm<14>(k4.w, m1);
      }
#pragma unroll
      for (int k = 0; k < 14; ++k) base[k] = m1[k];
    }
    __syncthreads();
    if (tid < 64) {
      const int rowc = tid >> 1, half = tid & 1;
      u32* rb = mg + rowc * 256 + half * 128;
      u32 m2[KM];
#pragma unroll
      for (int k = 0; k < KM; ++k) m2[k] = 0xffffffffu;
#pragma unroll
      for (int o = 0; o < 4; ++o) {
        const u32* p = rb + o * 32;
        for (int j = 0; j < 14; ++j) insmm<KM>(p[j], m2);
      }
#pragma unroll
      for (int k = 0; k < KM; ++k) rb[k] = m2[k];
    }
    __syncthreads();
    if (tid < 32) {
      u32 m3[KM];
#pragma unroll
      for (int k = 0; k < KM; ++k) m3[k] = 0xffffffffu;
      const u32* p0 = mg + tid * 256;
      for (int j = 0; j < KM; ++j) insmm<KM>(p0[j], m3);
      const u32* p1 = mg + tid * 256 + 128;
      for (int j = 0; j < KM; ++j) insmm<KM>(p1[j], m3);
      const int row = ((tid >> 4) << 5) + (chunk << 4) + (tid & 15);
      const int rg = (b << 13) + qbase + row;
      u16* cw = cand + (size_t)rg * (NPART * KM) + part * KM;
#pragma unroll
      for (int k = 0; k < KM; ++k)
        cw[k] = (u16)((part << 11) + (m3[k] & 0xfffu));
    }
    __syncthreads();
  }
}

// ---------------- kernel 3: bit-exact np-fp32 rescore + output ----------------
__global__ __launch_bounds__(512) void finalize_kernel(
    const float* __restrict__ pts, const float* __restrict__ sq,
    const u16* __restrict__ cand, int* __restrict__ out) {
  __shared__ u64 ex[64 * 81];
  __shared__ u64 hf[128 * 19];
  const int tid = threadIdx.x;
  const int rl = tid >> 3, sub = tid & 7;
  const int row = (blockIdx.x << 6) + rl;
  const int b = row >> 13;
  const float sqn = sq[row];
  const float* __restrict__ qrow = pts + ((size_t)row << 6);
  const float* __restrict__ sqb = sq + (b << 13);
  const u16* __restrict__ cr = cand + (size_t)row * 80 + sub * 10;
  u64* exw = ex + rl * 81 + sub * 10;
#pragma unroll 2
  for (int j = 0; j < 10; ++j) {
    const int ix = cr[j];
    const float* __restrict__ pv = pts + ((size_t)((b << 13) + ix) << 6);
    float dot = 0.f;
#pragma unroll
    for (int c = 0; c < CHN; ++c)
      dot = __fadd_rn(dot, __fmul_rn(qrow[c], pv[c]));
    const float dist =
        __fadd_rn(__fsub_rn(sqn, __fmul_rn(2.0f, dot)), sqb[ix]);
    exw[j] = ((u64)mono32(dist) << 32) | (u32)ix;
  }
  __syncthreads();
  if (tid < 128) {
    const int r2 = tid >> 1, hv = tid & 1;
    u64 m18[KF];
#pragma unroll
    for (int k = 0; k < KF; ++k) m18[k] = ~0ull;
    const u64* p = ex + r2 * 81 + hv * 40;
    for (int j = 0; j < 40; ++j) ins64<KF>(p[j], m18);
    u64* wr = hf + tid * 19;
#pragma unroll
    for (int k = 0; k < KF; ++k) wr[k] = m18[k];
  }
  __syncthreads();
  if (tid < 64) {
    u64 m18[KF];
#pragma unroll
    for (int k = 0; k < KF; ++k) m18[k] = ~0ull;
    const u64* p0 = hf + (tid << 1) * 19;
    const u64* p1 = hf + ((tid << 1) + 1) * 19;
    for (int j = 0; j < KF; ++j) ins64<KF>(p0[j], m18);
    for (int j = 0; j < KF; ++j) ins64<KF>(p1[j], m18);
    const int row2 = (blockIdx.x << 6) + tid;
    int* o0 = out + (size_t)row2 * KOUT;
    int* o1 = o0 + NB * NPTS * KOUT;
#pragma unroll
    for (int k = 0; k < KOUT; ++k) {
      o0[k] = (int)(m18[2 * k] & 0xffffffffu);
      o1[k] = row2 & 8191;
    }
  }
}

// ---------------- launcher ----------------
extern "C" void kernel_launch(void* const* d_in, const int* in_sizes, int n_in,
                              void* d_out, int out_size, void* d_ws, size_t ws_size,
                              hipStream_t stream) {
  const float* x = (const float*)d_in[0];
  u32* hib = (u32*)d_ws;                                // 2MB
  u32* lob = hib + (size_t)NB * NPTS * 32;              // 2MB
  float* pts = (float*)d_ws;                            // overlays hi/lo (4MB)
  float* sqg = (float*)(hib + (size_t)NB * NPTS * 64);  // @4MB, 64KB
  u16* cand = (u16*)(sqg + NB * NPTS);                  // 2.62MB
  int* out = (int*)d_out;
  prep_kernel<<<dim3(128), dim3(128), 0, stream>>>(x, hib, lob, sqg);
  knn_part_kernel<<<dim3(1024), dim3(256), 0, stream>>>(hib, lob, sqg, cand);
  prep2_kernel<<<dim3(128), dim3(128), 0, stream>>>(x, pts);
  finalize_kernel<<<dim3(256), dim3(512), 0, stream>>>(pts, sqg, cand, out);
}